// Round 8
// baseline (106.478 us; speedup 1.0000x reference)
//
#include <hip/hip_runtime.h>
#include <math.h>

// B=256; bilinear upsample 64/32/16 -> 256x256 (align_corners=True), sum -> maps;
// 5x5 gaussian blur (sigma=4, reflect); per-sample max -> scores.
//
// v9 = v7 geometry + rolling y-state (the combination the counters point to):
//   - QB=8 (32-row strips, 8 rows/wave): prologue amortized over 32 rows,
//     priming redundancy 1.5x (v8's QB=16 was 2x -> regressed)
//   - no xr0 (v7): LDS 16320 B -> 8 blocks/CU = 32 waves/CU; 2 barriers
//   - rolling y-state (fixes v7's LDS-pipe bound of 20 LDS ops/row):
//       scale0 advance = 8 scalar gathers from raw s0r, prob 63/255 -> ~2 reads/row
//       (lanes spread over cols 0..63 -> 2-way bank aliasing, free)
//       scale1/2 advance = one b128 from xr1/xr2, prob 31/255 / 15/255
//       steady state ~12 LDS-cyc/row vs v7's ~141
//   - rolling state 24 floats + window 20 + x-params 8 -> no spill under (256,4)
//     (v3's spill came from 3 scales of per-thread raw-lerp x-params; scales 1/2
//      now come pre-x-interpolated from LDS)
//   - control (y/rem) wave-uniform in SGPRs; vertical 5-tap in registers;
//     horizontal 5-tap via in-wave __shfl; per-wave reduce -> part[bid*4+wv]
// Kernel 2: partials -> scores (deterministic).

static constexpr int W  = 256;
static constexpr int QB = 8;             // blocks per sample (32 rows each)

__device__ __forceinline__ int reflect256(int i) {
    if (i < 0) i = -i;
    if (i > 255) i = 510 - i;
    return i;
}

__global__ __launch_bounds__(256, 4) void fused_kernel(
    const float* __restrict__ in0,   // [B,64,64]
    const float* __restrict__ in1,   // [B,32,32]
    const float* __restrict__ in2,   // [B,16,16]
    float* __restrict__ part,        // [B*QB*4] per-wave partial maxes
    float* __restrict__ maps)        // [B,256,256]
{
    const int t   = threadIdx.x;
    const int q   = t & 63;                                      // lane = column quad
    const int wv  = __builtin_amdgcn_readfirstlane(t >> 6);      // wave id (SGPR)
    const int bid = blockIdx.x;
    const int b   = bid >> 3;
    const int r0  = (bid & 7) * 32;
    const int rw0 = r0 + wv * 8;                                 // wave's first output row
    const int c0  = q * 4;

    // ---- source-row slice bounds (block-uniform); output rows r0-2 .. r0+33 ----
    const int rlo = max(r0 - 2, 0);
    const int rhi = min(r0 + 33, 255);
    const int y0lo = (rlo * 63) / 255;
    const int y1lo = (rlo * 31) / 255;
    const int y2lo = (rlo * 15) / 255;
    const int y0hi = min((rhi * 63) / 255 + 1, 63);
    const int y1hi = min((rhi * 31) / 255 + 1, 31);
    const int y2hi = min((rhi * 15) / 255 + 1, 15);
    const int n0 = y0hi - y0lo + 1;      // <= 11
    const int n1 = y1hi - y1lo + 1;      // <= 7
    const int n2 = y2hi - y2lo + 1;      // <= 5

    // ---- LDS layout (floats), 4080 * 4 = 16320 B -> 8 blocks/CU (wave cap) ----
    // [0,704)      s0r raw 11x64   (live whole kernel; scale0 gathered on advance)
    // [704,928)    s1r raw 7x32    (dead after x-interp phase)
    // [928,1008)   s2r raw 5x16    (dead after x-interp phase)
    // [1008,2800)  xr1 7x256
    // [2800,4080)  xr2 5x256
    __shared__ float lds[4080];
    float* const s0r = lds;
    float* const s1r = lds + 704;
    float* const s2r = lds + 928;
    float* const xr1 = lds + 1008;
    float* const xr2 = lds + 2800;

    // ---- stage raw slices (float4, coalesced) ----
    {
        const float4* g0 = (const float4*)(in0 + (size_t)b * 4096 + y0lo * 64);
        const float4* g1 = (const float4*)(in1 + (size_t)b * 1024 + y1lo * 32);
        const float4* g2 = (const float4*)(in2 + (size_t)b * 256  + y2lo * 16);
        if (t < n0 * 16) ((float4*)s0r)[t] = g0[t];
        if (t < n1 * 8)  ((float4*)s1r)[t] = g1[t];
        if (t < n2 * 4)  ((float4*)s2r)[t] = g2[t];
    }
    __syncthreads();

    const float inv255 = 1.0f / 255.0f;

    // ---- x-interp phase: scales 1,2 into xr1/xr2 (quad-vectorized, b128 writes) ----
    // 4 consecutive out-cols span < 2 source cells -> reads {x0, x0+1, x0+2} suffice.
    {
        const int T1 = n1 * 64;
        for (int task = t; task < T1; task += 256) {
            const int r = task >> 6, cq = (task & 63) * 4;
            const float* src = s1r + r * 32;
            const int x0 = (cq * 31) / 255;
            const float v0 = src[x0];
            const float v1 = src[min(x0 + 1, 31)];
            const float v2 = src[min(x0 + 2, 31)];
            float o[4];
#pragma unroll
            for (int k = 0; k < 4; ++k) {
                const int ix = (cq + k) * 31;
                const int xk = ix / 255;
                const float fx = (float)(ix - 255 * xk) * inv255;
                const float a  = (xk == x0) ? v0 : v1;
                const float bb = (xk == x0) ? v1 : v2;
                o[k] = a + fx * (bb - a);
            }
            *(float4*)(xr1 + r * 256 + cq) = make_float4(o[0], o[1], o[2], o[3]);
        }
        const int T2 = n2 * 64;
        for (int task = t; task < T2; task += 256) {
            const int r = task >> 6, cq = (task & 63) * 4;
            const float* src = s2r + r * 16;
            const int x0 = (cq * 15) / 255;
            const float v0 = src[x0];
            const float v1 = src[min(x0 + 1, 15)];
            const float v2 = src[min(x0 + 2, 15)];
            float o[4];
#pragma unroll
            for (int k = 0; k < 4; ++k) {
                const int ix = (cq + k) * 15;
                const int xk = ix / 255;
                const float fx = (float)(ix - 255 * xk) * inv255;
                const float a  = (xk == x0) ? v0 : v1;
                const float bb = (xk == x0) ? v1 : v2;
                o[k] = a + fx * (bb - a);
            }
            *(float4*)(xr2 + r * 256 + cq) = make_float4(o[0], o[1], o[2], o[3]);
        }
    }
    __syncthreads();

    // ---- per-column x-interp params for scale0 (4 columns per thread) ----
    int   x00[4];
    float fx0[4];
#pragma unroll
    for (int k = 0; k < 4; ++k) {
        int ix = (c0 + k) * 63;
        x00[k] = ix / 255;
        fx0[k] = (float)(ix - 255 * x00[k]) * inv255;
    }

    // x-interpolated scale0 row y (absolute) -> 4 cols, via raw gather (on advance only)
    auto xg0 = [&](int y, float* d) {
        const float* row = s0r + (y - y0lo) * 64;
#pragma unroll
        for (int k = 0; k < 4; ++k) {
            const int xa = x00[k], xb = min(xa + 1, 63);
            const float a = row[xa], bb = row[xb];
            d[k] = a + fx0[k] * (bb - a);
        }
    };
    auto ld1 = [&](int y, float* d) {
        const float4 v = *(const float4*)(xr1 + (y - y1lo) * 256 + c0);
        d[0] = v.x; d[1] = v.y; d[2] = v.z; d[3] = v.w;
    };
    auto ld2 = [&](int y, float* d) {
        const float4 v = *(const float4*)(xr2 + (y - y2lo) * 256 + c0);
        d[0] = v.x; d[1] = v.y; d[2] = v.z; d[3] = v.w;
    };

    // ---- rolling bilinear state (control wave-uniform -> SGPRs) ----
    int ya, yb, yc, rem0, rem1, rem2;
    float rl0[4], rh0[4], rl1[4], rh1[4], rl2[4], rh2[4];

    auto init_state = [&](int rn) {
        int iy;
        iy = rn * 63; ya = iy / 255; rem0 = iy - 255 * ya; xg0(ya, rl0); xg0(min(ya + 1, 63), rh0);
        iy = rn * 31; yb = iy / 255; rem1 = iy - 255 * yb; ld1(yb, rl1); ld1(min(yb + 1, 31), rh1);
        iy = rn * 15; yc = iy / 255; rem2 = iy - 255 * yc; ld2(yc, rl2); ld2(min(yc + 1, 15), rh2);
    };

    auto step = [&](float* o) {
        const float w0 = (float)rem0 * inv255;
        const float w1 = (float)rem1 * inv255;
        const float w2 = (float)rem2 * inv255;
#pragma unroll
        for (int k = 0; k < 4; ++k) {
            o[k] = (rl0[k] + w0 * (rh0[k] - rl0[k]))
                 + (rl1[k] + w1 * (rh1[k] - rl1[k]))
                 + (rl2[k] + w2 * (rh2[k] - rl2[k]));
        }
        // advance (wave-uniform; per-row increment < 1 -> at most one row each)
        rem0 += 63;
        if (rem0 >= 255) {
            rem0 -= 255; ++ya;
#pragma unroll
            for (int k = 0; k < 4; ++k) rl0[k] = rh0[k];
            xg0(min(ya + 1, 63), rh0);
        }
        rem1 += 31;
        if (rem1 >= 255) {
            rem1 -= 255; ++yb;
#pragma unroll
            for (int k = 0; k < 4; ++k) rl1[k] = rh1[k];
            ld1(min(yb + 1, 31), rh1);
        }
        rem2 += 15;
        if (rem2 >= 255) {
            rem2 -= 255; ++yc;
#pragma unroll
            for (int k = 0; k < 4; ++k) rl2[k] = rh2[k];
            ld2(min(yc + 1, 15), rh2);
        }
    };

    // full bilinear sample of map row rn (reflects internally) — priming/tail only
    auto direct4 = [&](int rn, float* o) {
        const int ry = reflect256(rn);
        int iy = ry * 63; int a0 = iy / 255; float w0 = (float)(iy - 255 * a0) * inv255; int a1 = min(a0 + 1, 63);
        int ib = ry * 31; int b0 = ib / 255; float w1 = (float)(ib - 255 * b0) * inv255; int b1 = min(b0 + 1, 31);
        int ic = ry * 15; int cc0 = ic / 255; float w2 = (float)(ic - 255 * cc0) * inv255; int cc1 = min(cc0 + 1, 15);
        float l0[4], h0[4], l1[4], h1[4], l2[4], h2[4];
        xg0(a0, l0); xg0(a1, h0);
        ld1(b0, l1); ld1(b1, h1);
        ld2(cc0, l2); ld2(cc1, h2);
#pragma unroll
        for (int k = 0; k < 4; ++k) {
            o[k] = (l0[k] + w0 * (h0[k] - l0[k]))
                 + (l1[k] + w1 * (h1[k] - l1[k]))
                 + (l2[k] + w2 * (h2[k] - l2[k]));
        }
    };

    // ---- gaussian weights (ksize=5, sigma=4) ----
    const float e1 = expf(-1.0f / 32.0f);
    const float e2 = expf(-4.0f / 32.0f);
    const float nrm = 1.0f + 2.0f * e1 + 2.0f * e2;
    const float gwc = 1.0f / nrm, gwa = e1 / nrm, gwb = e2 / nrm;

    // ---- prime 4-row blur window: map rows rw0-2 .. rw0+1 ----
    float m0[4], m1[4], m2[4], m3[4], mn[4];
    if (rw0 == 0) {                      // reflected top rows: -2 -> 2, -1 -> 1
        direct4(2, m0);
        direct4(1, m1);
        direct4(0, m2);
#pragma unroll
        for (int k = 0; k < 4; ++k) m3[k] = m1[k];
        init_state(2);                   // ready to produce rn = 2
    } else {
        init_state(rw0 - 2);
        step(m0); step(m1); step(m2); step(m3);   // state now at rn = rw0+2
    }

    float* __restrict__ mpr = maps + ((size_t)b * W + (size_t)rw0) * W + c0;
    *(float4*)(mpr)     = make_float4(m2[0], m2[1], m2[2], m2[3]);
    *(float4*)(mpr + W) = make_float4(m3[0], m3[1], m3[2], m3[3]);

    float gmax = -INFINITY;

#pragma unroll
    for (int i = 0; i < 8; ++i) {
        const int rn = rw0 + 2 + i;
        if (rn <= 255) step(mn);
        else           direct4(rn, mn);  // reflected rows 256/257 (last strip only)

        if (i < 6)                       // rows rw0+2 .. rw0+7 are ours
            *(float4*)(mpr + (size_t)(2 + i) * W) = make_float4(mn[0], mn[1], mn[2], mn[3]);

        // vertical 5-tap for blur row rw0+i (in registers)
        float vr0 = gwb * (m0[0] + mn[0]) + gwa * (m1[0] + m3[0]) + gwc * m2[0];
        float vr1 = gwb * (m0[1] + mn[1]) + gwa * (m1[1] + m3[1]) + gwc * m2[1];
        float vr2 = gwb * (m0[2] + mn[2]) + gwa * (m1[2] + m3[2]) + gwc * m2[2];
        float vr3 = gwb * (m0[3] + mn[3]) + gwa * (m1[3] + m3[3]) + gwc * m2[3];
#pragma unroll
        for (int k = 0; k < 4; ++k) { m0[k] = m1[k]; m1[k] = m2[k]; m2[k] = m3[k]; m3[k] = mn[k]; }

        // horizontal 5-tap: neighbor-quad edge columns via in-wave shuffles
        float az = __shfl_up(vr2, 1);        // col c0-2 from left lane
        float aw = __shfl_up(vr3, 1);        // col c0-1
        float cx = __shfl_down(vr0, 1);      // col c0+4 from right lane
        float cy = __shfl_down(vr1, 1);      // col c0+5
        float a2 = (q == 0)  ? vr2 : az;     // reflect at col 0
        float a3 = (q == 0)  ? vr1 : aw;
        float c4 = (q == 63) ? vr2 : cx;     // reflect at col 255
        float c5 = (q == 63) ? vr1 : cy;
        float o0 = gwc * vr0 + gwa * (a3 + vr1)  + gwb * (a2 + vr2);
        float o1 = gwc * vr1 + gwa * (vr0 + vr2) + gwb * (a3 + vr3);
        float o2 = gwc * vr2 + gwa * (vr1 + vr3) + gwb * (vr0 + c4);
        float o3 = gwc * vr3 + gwa * (vr2 + c4)  + gwb * (vr1 + c5);
        gmax = fmaxf(gmax, fmaxf(fmaxf(o0, o1), fmaxf(o2, o3)));
    }

    // ---- per-wave max -> partial (no extra barrier) ----
#pragma unroll
    for (int off = 32; off > 0; off >>= 1)
        gmax = fmaxf(gmax, __shfl_down(gmax, off));
    if (q == 0) part[bid * 4 + wv] = gmax;
}

__global__ void reduce_kernel(const float* __restrict__ part,
                              float* __restrict__ scores, int B) {
    int i = blockIdx.x * blockDim.x + threadIdx.x;
    if (i < B) {
        const float4* p = (const float4*)(part + 32 * i);   // QB*4 = 32 partials
        float m = -INFINITY;
#pragma unroll
        for (int k = 0; k < 8; ++k) {
            float4 v = p[k];
            m = fmaxf(m, fmaxf(fmaxf(v.x, v.y), fmaxf(v.z, v.w)));
        }
        scores[i] = m;
    }
}

extern "C" void kernel_launch(void* const* d_in, const int* in_sizes, int n_in,
                              void* d_out, int out_size, void* d_ws, size_t ws_size,
                              hipStream_t stream) {
    const float* in0 = (const float*)d_in[0];
    const float* in1 = (const float*)d_in[1];
    const float* in2 = (const float*)d_in[2];
    const int B = in_sizes[0] / (64 * 64);

    float* scores = (float*)d_out;
    float* maps   = (float*)d_out + B;
    float* part   = (float*)d_ws;          // B*QB*4 floats, fully rewritten each call

    hipLaunchKernelGGL(fused_kernel, dim3(B * QB), dim3(256), 0, stream,
                       in0, in1, in2, part, maps);
    hipLaunchKernelGGL(reduce_kernel, dim3((B + 255) / 256), dim3(256), 0, stream,
                       part, scores, B);
}

// Round 10
// 90.317 us; speedup vs baseline: 1.1789x; 1.1789x over previous
//
#include <hip/hip_runtime.h>
#include <math.h>

// B=256; bilinear upsample 64/32/16 -> 256x256 (align_corners=True), sum -> maps;
// 5x5 gaussian blur (sigma=4, reflect); per-sample max -> scores.
//
// v10b = v5 (measured champion, 91.3 us total) + non-temporal map stores.
//   (v10 failed to compile: __builtin_nontemporal_store rejects HIP_vector_type
//    float4*; use a native ext_vector_type(4) float instead — identical layout.)
//   Round 5-8 A/B series: QB=16 (92.1), no-xr0 scalar gather (96.9), rolling
//   y-state QB=16 (99.7), rolling QB=8 (106.5) -- ALL regressed vs v5. Fused
//   lands 40-46 us across structures with 20x different LDS-op counts ->
//   mixed VALU+latency bound; structural churn is neutral-to-negative.
//   Restoring v5 exactly; only delta: NT stores for maps (write-once stream,
//   never re-read here -> don't pollute L2).
//   - grid = B*8 blocks x 256 threads (4 waves), 32-row strip/block, 8 rows/wave,
//     64 lanes x 4 cols (float4 everywhere)
//   - per block: stage raw source-row slices (float4); x-interp scales 1,2 into
//     xr1/xr2; barrier; x-interp scale 0 into xr0 (aliases dead s1r/s2r); barrier
//   - per output row: wave-uniform (y,fy) per scale + 6 aligned float4 LDS reads
//   - per-thread state ~ blur window only (~40-64 VGPR, no spill)
//   - LDS 26368 B -> 6 blocks/CU = 24 waves/CU
//   - vertical 5-tap in registers; horizontal 5-tap via in-wave __shfl
//   - per-wave shuffle-reduce max -> part[bid*4+wv]
// Kernel 2: partials -> scores (deterministic).

static constexpr int W  = 256;
static constexpr int QB = 8;             // blocks per sample (32 rows each)

typedef float f4 __attribute__((ext_vector_type(4)));   // native vec for NT stores

__device__ __forceinline__ int reflect256(int i) {
    if (i < 0) i = -i;
    if (i > 255) i = 510 - i;
    return i;
}

__device__ __forceinline__ void nt_store4(float* p, float a, float b, float c, float d) {
    f4 v; v.x = a; v.y = b; v.z = c; v.w = d;
    __builtin_nontemporal_store(v, (f4*)p);
}

__global__ __launch_bounds__(256, 4) void fused_kernel(
    const float* __restrict__ in0,   // [B,64,64]
    const float* __restrict__ in1,   // [B,32,32]
    const float* __restrict__ in2,   // [B,16,16]
    float* __restrict__ part,        // [B*QB*4] per-wave partial maxes
    float* __restrict__ maps)        // [B,256,256]
{
    const int t   = threadIdx.x;
    const int q   = t & 63;                                      // lane = column quad
    const int wv  = __builtin_amdgcn_readfirstlane(t >> 6);      // wave id (SGPR)
    const int bid = blockIdx.x;
    const int b   = bid >> 3;
    const int r0  = (bid & 7) * 32;
    const int rw0 = r0 + wv * 8;                                 // wave's first output row
    const int c0  = q * 4;

    // ---- source-row slice bounds (block-uniform) ----
    const int rlo = max(r0 - 2, 0);
    const int rhi = min(r0 + 33, 255);
    const int y0lo = (rlo * 63) / 255;
    const int y1lo = (rlo * 31) / 255;
    const int y2lo = (rlo * 15) / 255;
    const int y0hi = min((rhi * 63) / 255 + 1, 63);
    const int y1hi = min((rhi * 31) / 255 + 1, 31);
    const int y2hi = min((rhi * 15) / 255 + 1, 15);
    const int n0 = y0hi - y0lo + 1;      // <= 11
    const int n1 = y1hi - y1lo + 1;      // <= 7
    const int n2 = y2hi - y2lo + 1;      // <= 5

    // ---- LDS layout (floats), 6592 * 4 = 26368 B -> 6 blocks/CU ----
    // [0,704)      s0r raw 11x64
    // [704,928)    s1r raw 7x32   (dead after phase A)
    // [928,1008)   s2r raw 5x16   (dead after phase A)
    // [704,3520)   xr0 11x256     (phase B output, aliases s1r/s2r)
    // [3520,5312)  xr1 7x256
    // [5312,6592)  xr2 5x256
    __shared__ float lds[6592];
    float* const s0r = lds;
    float* const s1r = lds + 704;
    float* const s2r = lds + 928;
    float* const xr0 = lds + 704;
    float* const xr1 = lds + 3520;
    float* const xr2 = lds + 5312;

    // ---- stage raw slices (float4, coalesced) ----
    {
        const float4* g0 = (const float4*)(in0 + (size_t)b * 4096 + y0lo * 64);
        const float4* g1 = (const float4*)(in1 + (size_t)b * 1024 + y1lo * 32);
        const float4* g2 = (const float4*)(in2 + (size_t)b * 256  + y2lo * 16);
        if (t < n0 * 16) ((float4*)s0r)[t] = g0[t];
        if (t < n1 * 8)  ((float4*)s1r)[t] = g1[t];
        if (t < n2 * 4)  ((float4*)s2r)[t] = g2[t];
    }
    __syncthreads();

    const float inv255 = 1.0f / 255.0f;

    // ---- phase A: x-interp scales 1,2 (one output column per thread) ----
    {
        int ix = t * 31; int xa = ix / 255; float fx = (float)(ix - 255 * xa) * inv255; int xb = min(xa + 1, 31);
        for (int r = 0; r < n1; ++r) {
            float a = s1r[r * 32 + xa], bv = s1r[r * 32 + xb];
            xr1[r * 256 + t] = a + fx * (bv - a);
        }
        ix = t * 15; xa = ix / 255; fx = (float)(ix - 255 * xa) * inv255; xb = min(xa + 1, 15);
        for (int r = 0; r < n2; ++r) {
            float a = s2r[r * 16 + xa], bv = s2r[r * 16 + xb];
            xr2[r * 256 + t] = a + fx * (bv - a);
        }
    }
    __syncthreads();                      // s1r/s2r dead; xr0 may overwrite them

    // ---- phase B: x-interp scale 0 (s0r untouched by xr0) ----
    {
        int ix = t * 63; int xa = ix / 255; float fx = (float)(ix - 255 * xa) * inv255; int xb = min(xa + 1, 63);
        for (int r = 0; r < n0; ++r) {
            float a = s0r[r * 64 + xa], bv = s0r[r * 64 + xb];
            xr0[r * 256 + t] = a + fx * (bv - a);
        }
    }
    __syncthreads();

    // ---- per-row sampler: wave-uniform (y,fy) per scale + 6 aligned float4 LDS reads ----
    auto sample = [&](int rn, float* o) {
        const int ry = reflect256(rn);
        int iy = ry * 63; int ya = iy / 255; float w0 = (float)(iy - 255 * ya) * inv255; int ya1 = min(ya + 1, 63);
        int ib = ry * 31; int yb = ib / 255; float w1 = (float)(ib - 255 * yb) * inv255; int yb1 = min(yb + 1, 31);
        int ic = ry * 15; int yc = ic / 255; float w2 = (float)(ic - 255 * yc) * inv255; int yc1 = min(yc + 1, 15);
        const float4 l0 = *(const float4*)(xr0 + (ya  - y0lo) * 256 + c0);
        const float4 h0 = *(const float4*)(xr0 + (ya1 - y0lo) * 256 + c0);
        const float4 l1 = *(const float4*)(xr1 + (yb  - y1lo) * 256 + c0);
        const float4 h1 = *(const float4*)(xr1 + (yb1 - y1lo) * 256 + c0);
        const float4 l2 = *(const float4*)(xr2 + (yc  - y2lo) * 256 + c0);
        const float4 h2 = *(const float4*)(xr2 + (yc1 - y2lo) * 256 + c0);
        o[0] = (l0.x + w0 * (h0.x - l0.x)) + (l1.x + w1 * (h1.x - l1.x)) + (l2.x + w2 * (h2.x - l2.x));
        o[1] = (l0.y + w0 * (h0.y - l0.y)) + (l1.y + w1 * (h1.y - l1.y)) + (l2.y + w2 * (h2.y - l2.y));
        o[2] = (l0.z + w0 * (h0.z - l0.z)) + (l1.z + w1 * (h1.z - l1.z)) + (l2.z + w2 * (h2.z - l2.z));
        o[3] = (l0.w + w0 * (h0.w - l0.w)) + (l1.w + w1 * (h1.w - l1.w)) + (l2.w + w2 * (h2.w - l2.w));
    };

    // ---- gaussian weights (ksize=5, sigma=4) ----
    const float e1 = expf(-1.0f / 32.0f);
    const float e2 = expf(-4.0f / 32.0f);
    const float nrm = 1.0f + 2.0f * e1 + 2.0f * e2;
    const float gwc = 1.0f / nrm, gwa = e1 / nrm, gwb = e2 / nrm;

    // ---- prime 4-row blur window (reflect handles rw0==0) ----
    float m0[4], m1[4], m2[4], m3[4], mn[4];
    sample(rw0 - 2, m0);
    sample(rw0 - 1, m1);
    sample(rw0,     m2);
    sample(rw0 + 1, m3);

    float* __restrict__ mpr = maps + ((size_t)b * W + (size_t)rw0) * W + c0;
    nt_store4(mpr,     m2[0], m2[1], m2[2], m2[3]);
    nt_store4(mpr + W, m3[0], m3[1], m3[2], m3[3]);

    float gmax = -INFINITY;

#pragma unroll
    for (int i = 0; i < 8; ++i) {
        sample(rw0 + 2 + i, mn);         // reflect handles rows 256/257 (last strip)

        if (i < 6)                       // rows rw0+2 .. rw0+7 are ours
            nt_store4(mpr + (size_t)(2 + i) * W, mn[0], mn[1], mn[2], mn[3]);

        // vertical 5-tap for blur row rw0+i (in registers)
        float vr0 = gwb * (m0[0] + mn[0]) + gwa * (m1[0] + m3[0]) + gwc * m2[0];
        float vr1 = gwb * (m0[1] + mn[1]) + gwa * (m1[1] + m3[1]) + gwc * m2[1];
        float vr2 = gwb * (m0[2] + mn[2]) + gwa * (m1[2] + m3[2]) + gwc * m2[2];
        float vr3 = gwb * (m0[3] + mn[3]) + gwa * (m1[3] + m3[3]) + gwc * m2[3];
#pragma unroll
        for (int k = 0; k < 4; ++k) { m0[k] = m1[k]; m1[k] = m2[k]; m2[k] = m3[k]; m3[k] = mn[k]; }

        // horizontal 5-tap: neighbor-quad edge columns via in-wave shuffles
        float az = __shfl_up(vr2, 1);        // col c0-2 from left lane
        float aw = __shfl_up(vr3, 1);        // col c0-1
        float cx = __shfl_down(vr0, 1);      // col c0+4 from right lane
        float cy = __shfl_down(vr1, 1);      // col c0+5
        float a2 = (q == 0)  ? vr2 : az;     // reflect at col 0
        float a3 = (q == 0)  ? vr1 : aw;
        float c4 = (q == 63) ? vr2 : cx;     // reflect at col 255
        float c5 = (q == 63) ? vr1 : cy;
        float o0 = gwc * vr0 + gwa * (a3 + vr1)  + gwb * (a2 + vr2);
        float o1 = gwc * vr1 + gwa * (vr0 + vr2) + gwb * (a3 + vr3);
        float o2 = gwc * vr2 + gwa * (vr1 + vr3) + gwb * (vr0 + c4);
        float o3 = gwc * vr3 + gwa * (vr2 + c4)  + gwb * (vr1 + c5);
        gmax = fmaxf(gmax, fmaxf(fmaxf(o0, o1), fmaxf(o2, o3)));
    }

    // ---- per-wave max -> partial (no extra barrier) ----
#pragma unroll
    for (int off = 32; off > 0; off >>= 1)
        gmax = fmaxf(gmax, __shfl_down(gmax, off));
    if (q == 0) part[bid * 4 + wv] = gmax;
}

__global__ void reduce_kernel(const float* __restrict__ part,
                              float* __restrict__ scores, int B) {
    int i = blockIdx.x * blockDim.x + threadIdx.x;
    if (i < B) {
        const float4* p = (const float4*)(part + 32 * i);   // QB*4 = 32 partials
        float m = -INFINITY;
#pragma unroll
        for (int k = 0; k < 8; ++k) {
            float4 v = p[k];
            m = fmaxf(m, fmaxf(fmaxf(v.x, v.y), fmaxf(v.z, v.w)));
        }
        scores[i] = m;
    }
}

extern "C" void kernel_launch(void* const* d_in, const int* in_sizes, int n_in,
                              void* d_out, int out_size, void* d_ws, size_t ws_size,
                              hipStream_t stream) {
    const float* in0 = (const float*)d_in[0];
    const float* in1 = (const float*)d_in[1];
    const float* in2 = (const float*)d_in[2];
    const int B = in_sizes[0] / (64 * 64);

    float* scores = (float*)d_out;
    float* maps   = (float*)d_out + B;
    float* part   = (float*)d_ws;          // B*QB*4 floats, fully rewritten each call

    hipLaunchKernelGGL(fused_kernel, dim3(B * QB), dim3(256), 0, stream,
                       in0, in1, in2, part, maps);
    hipLaunchKernelGGL(reduce_kernel, dim3((B + 255) / 256), dim3(256), 0, stream,
                       part, scores, B);
}